// Round 1
// baseline (3802.402 us; speedup 1.0000x reference)
//
#include <hip/hip_runtime.h>

#define BB   256   // batch
#define IND  128   // input dim
#define HD   512   // hidden dim
#define G    4     // batch rows per block
#define NBLK (BB/G)
#define KST  16    // uniform RK4 steps per row

__device__ __forceinline__ float sigm(float x){ return 1.0f/(1.0f+__expf(-x)); }
// NaN-safe tanh via exp: large +x -> 1, large -x -> -1
__device__ __forceinline__ float tanhfast(float x){
  float e2 = __expf(2.0f*x);
  return 1.0f - 2.0f/(e2+1.0f);
}

// ---------------- LSTM cell: gates GEMM + activations ----------------
// grid: NBLK blocks x 256 thr; block owns batch rows [4b, 4b+4)
// thread t computes gate columns n = t + 256*q, q=0..7  (i,f,g,o interleaved)
__global__ __launch_bounds__(256) void k_gates(
    const float* __restrict__ inp, const float* __restrict__ h,
    const float* __restrict__ c,   const float* __restrict__ Wih,
    const float* __restrict__ Whh, const float* __restrict__ bih,
    const float* __restrict__ bhh, float* __restrict__ h0,
    float* __restrict__ newc){
  __shared__ __align__(16) float sx[G*IND];
  __shared__ __align__(16) float sh[G*HD];
  const int t  = threadIdx.x;
  const int r0 = blockIdx.x*G;
  #pragma unroll
  for (int i=0;i<G*IND/256;i++) sx[t+256*i] = inp[r0*IND + t+256*i];
  #pragma unroll
  for (int i=0;i<G*HD/256;i++)  sh[t+256*i] = h[r0*HD + t+256*i];
  __syncthreads();

  float acc[G][8];
  #pragma unroll
  for (int r=0;r<G;r++){
    #pragma unroll
    for (int q=0;q<8;q++) acc[r][q]=0.f;
  }
  // x @ W_ih^T
  for (int k0=0;k0<IND;k0+=4){
    float4 w[8];
    #pragma unroll
    for (int q=0;q<8;q++) w[q] = *(const float4*)(Wih + (t+256*q)*IND + k0);
    #pragma unroll
    for (int r=0;r<G;r++){
      float4 x = *(const float4*)(sx + r*IND + k0);
      #pragma unroll
      for (int q=0;q<8;q++)
        acc[r][q] += x.x*w[q].x + x.y*w[q].y + x.z*w[q].z + x.w*w[q].w;
    }
  }
  // h @ W_hh^T
  for (int k0=0;k0<HD;k0+=4){
    float4 w[8];
    #pragma unroll
    for (int q=0;q<8;q++) w[q] = *(const float4*)(Whh + (t+256*q)*HD + k0);
    #pragma unroll
    for (int r=0;r<G;r++){
      float4 x = *(const float4*)(sh + r*HD + k0);
      #pragma unroll
      for (int q=0;q<8;q++)
        acc[r][q] += x.x*w[q].x + x.y*w[q].y + x.z*w[q].z + x.w*w[q].w;
    }
  }
  // gate order (PyTorch): n in [0,512)=i, [512,1024)=f, [1024,1536)=g, [1536,2048)=o
  // q=p   -> i-gate for hi = t+256p ; q=2+p -> f ; q=4+p -> g ; q=6+p -> o
  #pragma unroll
  for (int p=0;p<2;p++){
    const int hi = t + 256*p;
    const float bi = bih[hi]      + bhh[hi];
    const float bf = bih[512+hi]  + bhh[512+hi];
    const float bg = bih[1024+hi] + bhh[1024+hi];
    const float bo = bih[1536+hi] + bhh[1536+hi];
    #pragma unroll
    for (int r=0;r<G;r++){
      const float iv = acc[r][0+p]+bi;
      const float fv = acc[r][2+p]+bf;
      const float gv = acc[r][4+p]+bg;
      const float ov = acc[r][6+p]+bo;
      const float cv = c[(r0+r)*HD + hi];
      const float nc = sigm(fv)*cv + sigm(iv)*tanhfast(gv);
      const float hv = sigm(ov)*tanhfast(nc);
      newc[(r0+r)*HD + hi] = nc;
      h0[(r0+r)*HD + hi]   = hv;
    }
  }
}

// ---------------- stable argsort + per-row integration duration ----------------
// tau[j] = s_sort[indices[j]] - s_sort[0], with s_sort[r] = ts_sorted[r] + r*1e-4/255
__global__ void k_sort(const float* __restrict__ ts, float* __restrict__ tau){
  __shared__ float sts[BB];
  __shared__ float ssort[BB];
  __shared__ int   sidx[BB];
  const int t = threadIdx.x;
  sts[t] = ts[t];
  __syncthreads();
  const float v = sts[t];
  int r = 0;
  for (int k=0;k<BB;k++){
    const float u = sts[k];
    r += (u < v) || (u == v && k < t);   // stable rank
  }
  ssort[r] = v + (float)r*(1e-4f/255.0f);
  sidx[r]  = t;                          // sidx == indices (argsort result)
  __syncthreads();
  const int n = sidx[t];                 // indices[t] = steps row t takes in reference
  tau[t] = ssort[n] - ssort[0];
}

// ---------------- ODE RK4 evolve ----------------
// matvec-set: out{0,1}[r] = sum_k IN[r][k] * W[{t,t+256}][k]   (W row-major [out][in])
__device__ __forceinline__ void mv_acc(const float* __restrict__ IN,
    const float* __restrict__ W, int t, float out0[G], float out1[G]){
  #pragma unroll
  for (int r=0;r<G;r++){ out0[r]=0.f; out1[r]=0.f; }
  const float* Wr0 = W + t*HD;
  const float* Wr1 = W + (t+256)*HD;
  for (int k0=0;k0<HD;k0+=4){
    const float4 w0 = *(const float4*)(Wr0+k0);
    const float4 w1 = *(const float4*)(Wr1+k0);
    #pragma unroll
    for (int r=0;r<G;r++){
      const float4 x = *(const float4*)(IN + r*HD + k0);
      out0[r] += x.x*w0.x + x.y*w0.y + x.z*w0.z + x.w*w0.w;
      out1[r] += x.x*w1.x + x.y*w1.y + x.z*w1.z + x.w*w1.w;
    }
  }
}

__global__ __launch_bounds__(256) void k_ode(
    const float* __restrict__ h0, const float* __restrict__ tau,
    const float* __restrict__ W1, const float* __restrict__ b1,
    const float* __restrict__ W2, const float* __restrict__ b2,
    float* __restrict__ newh){
  __shared__ __align__(16) float X [G*HD];
  __shared__ __align__(16) float XT[G*HD];
  __shared__ __align__(16) float Y [G*HD];
  const int t  = threadIdx.x;
  const int r0 = blockIdx.x*G;
  #pragma unroll
  for (int i=0;i<G*HD/256;i++) X[t+256*i] = h0[r0*HD + t+256*i];
  float dt[G];
  #pragma unroll
  for (int r=0;r<G;r++) dt[r] = tau[r0+r]*(1.0f/(float)KST);
  const float b1a=b1[t], b1b=b1[t+256], b2a=b2[t], b2b=b2[t+256];
  __syncthreads();

  float ac[G][2];   // k1 + 2k2 + 2k3 accumulator (this thread's elements only)
  for (int s=0;s<KST;s++){
    #pragma unroll
    for (int st=0; st<4; st++){
      const float* src = (st==0)? X : XT;
      // layer 1: Y = tanh(src @ W1^T + b1)
      {
        float a0[G], a1[G];
        mv_acc(src, W1, t, a0, a1);
        #pragma unroll
        for (int r=0;r<G;r++){
          Y[r*HD + t]       = tanhfast(a0[r]+b1a);
          Y[r*HD + t + 256] = tanhfast(a1[r]+b1b);
        }
      }
      __syncthreads();
      // layer 2: kv = Y @ W2^T + b2 (kept in registers), then RK4 combine
      {
        float a0[G], a1[G];
        mv_acc(Y, W2, t, a0, a1);
        #pragma unroll
        for (int r=0;r<G;r++){
          #pragma unroll
          for (int p=0;p<2;p++){
            const int   e  = r*HD + t + 256*p;
            const float kv = (p==0 ? a0[r]+b2a : a1[r]+b2b);
            if      (st==0){ ac[r][p] = kv;      XT[e] = X[e] + 0.5f*dt[r]*kv; }
            else if (st==1){ ac[r][p] += 2.f*kv; XT[e] = X[e] + 0.5f*dt[r]*kv; }
            else if (st==2){ ac[r][p] += 2.f*kv; XT[e] = X[e] + dt[r]*kv;      }
            else           { X[e] += (dt[r]*(1.f/6.f))*(ac[r][p] + kv);        }
          }
        }
      }
      __syncthreads();
    }
  }
  #pragma unroll
  for (int i=0;i<G*HD/256;i++) newh[r0*HD + t+256*i] = X[t+256*i];
}

// ---------------- launcher ----------------
extern "C" void kernel_launch(void* const* d_in, const int* in_sizes, int n_in,
                              void* d_out, int out_size, void* d_ws, size_t ws_size,
                              hipStream_t stream){
  const float* inp = (const float*)d_in[0];
  const float* h   = (const float*)d_in[1];
  const float* c   = (const float*)d_in[2];
  const float* ts  = (const float*)d_in[3];
  const float* Wih = (const float*)d_in[4];
  const float* Whh = (const float*)d_in[5];
  const float* bih = (const float*)d_in[6];
  const float* bhh = (const float*)d_in[7];
  const float* W1  = (const float*)d_in[8];
  const float* b1  = (const float*)d_in[9];
  const float* W2  = (const float*)d_in[10];
  const float* b2  = (const float*)d_in[11];

  float* newh = (float*)d_out;            // [256,512]
  float* newc = (float*)d_out + BB*HD;    // [256,512]
  float* h0   = (float*)d_ws;             // [256,512] scratch
  float* tau  = h0 + BB*HD;               // [256]

  k_gates<<<NBLK,256,0,stream>>>(inp,h,c,Wih,Whh,bih,bhh,h0,newc);
  k_sort <<<1,   BB, 0,stream>>>(ts,tau);
  k_ode  <<<NBLK,256,0,stream>>>(h0,tau,W1,b1,W2,b2,newh);
}

// Round 2
// 1866.067 us; speedup vs baseline: 2.0377x; 2.0377x over previous
//
#include <hip/hip_runtime.h>

#define BB   256   // batch
#define IND  128   // input dim
#define HD   512   // hidden dim
#define KST  16    // uniform RK4 steps per row
#define G    8     // real rows per ode block
#define ODE_BLOCKS (BB/G)   // 32
#define VSTR 520   // padded LDS row stride in halfs (1040 B)

typedef _Float16 f16x8 __attribute__((ext_vector_type(8)));
typedef float    f32x4 __attribute__((ext_vector_type(4)));

__device__ __forceinline__ float sigm(float x){ return 1.0f/(1.0f+__expf(-x)); }
__device__ __forceinline__ float tanhfast(float x){
  float e2 = __expf(2.0f*x);
  return 1.0f - 2.0f/(e2+1.0f);
}

// ---------------- LSTM cell: gates GEMM + activations (unchanged) ----------------
__global__ __launch_bounds__(256) void k_gates(
    const float* __restrict__ inp, const float* __restrict__ h,
    const float* __restrict__ c,   const float* __restrict__ Wih,
    const float* __restrict__ Whh, const float* __restrict__ bih,
    const float* __restrict__ bhh, float* __restrict__ h0,
    float* __restrict__ newc){
  __shared__ __align__(16) float sx[4*IND];
  __shared__ __align__(16) float sh[4*HD];
  const int t  = threadIdx.x;
  const int r0 = blockIdx.x*4;
  #pragma unroll
  for (int i=0;i<4*IND/256;i++) sx[t+256*i] = inp[r0*IND + t+256*i];
  #pragma unroll
  for (int i=0;i<4*HD/256;i++)  sh[t+256*i] = h[r0*HD + t+256*i];
  __syncthreads();

  float acc[4][8];
  #pragma unroll
  for (int r=0;r<4;r++){
    #pragma unroll
    for (int q=0;q<8;q++) acc[r][q]=0.f;
  }
  for (int k0=0;k0<IND;k0+=4){
    float4 w[8];
    #pragma unroll
    for (int q=0;q<8;q++) w[q] = *(const float4*)(Wih + (t+256*q)*IND + k0);
    #pragma unroll
    for (int r=0;r<4;r++){
      float4 x = *(const float4*)(sx + r*IND + k0);
      #pragma unroll
      for (int q=0;q<8;q++)
        acc[r][q] += x.x*w[q].x + x.y*w[q].y + x.z*w[q].z + x.w*w[q].w;
    }
  }
  for (int k0=0;k0<HD;k0+=4){
    float4 w[8];
    #pragma unroll
    for (int q=0;q<8;q++) w[q] = *(const float4*)(Whh + (t+256*q)*HD + k0);
    #pragma unroll
    for (int r=0;r<4;r++){
      float4 x = *(const float4*)(sh + r*HD + k0);
      #pragma unroll
      for (int q=0;q<8;q++)
        acc[r][q] += x.x*w[q].x + x.y*w[q].y + x.z*w[q].z + x.w*w[q].w;
    }
  }
  #pragma unroll
  for (int p=0;p<2;p++){
    const int hi = t + 256*p;
    const float bi = bih[hi]      + bhh[hi];
    const float bf = bih[512+hi]  + bhh[512+hi];
    const float bg = bih[1024+hi] + bhh[1024+hi];
    const float bo = bih[1536+hi] + bhh[1536+hi];
    #pragma unroll
    for (int r=0;r<4;r++){
      const float iv = acc[r][0+p]+bi;
      const float fv = acc[r][2+p]+bf;
      const float gv = acc[r][4+p]+bg;
      const float ov = acc[r][6+p]+bo;
      const float cv = c[(r0+r)*HD + hi];
      const float nc = sigm(fv)*cv + sigm(iv)*tanhfast(gv);
      const float hv = sigm(ov)*tanhfast(nc);
      newc[(r0+r)*HD + hi] = nc;
      h0[(r0+r)*HD + hi]   = hv;
    }
  }
}

// ---------------- stable argsort + per-row integration duration ----------------
__global__ void k_sort(const float* __restrict__ ts, float* __restrict__ tau){
  __shared__ float sts[BB];
  __shared__ float ssort[BB];
  __shared__ int   sidx[BB];
  const int t = threadIdx.x;
  sts[t] = ts[t];
  __syncthreads();
  const float v = sts[t];
  int r = 0;
  for (int k=0;k<BB;k++){
    const float u = sts[k];
    r += (u < v) || (u == v && k < t);
  }
  ssort[r] = v + (float)r*(1e-4f/255.0f);
  sidx[r]  = t;
  __syncthreads();
  const int n = sidx[t];
  tau[t] = ssort[n] - ssort[0];
}

// ---------------- pack W (fp32 row-major [512][512]) into f16 MFMA B-fragment order ----
// tile = NT*16+kt; lane l holds W[NT*16+(l&15)][kt*32+8*(l>>4) + j], j=0..7
__global__ void k_pack(const float* __restrict__ W, _Float16* __restrict__ Wp){
  const int tile = blockIdx.x;     // 0..511
  const int l = threadIdx.x;       // 0..63
  const int m = l & 15, g = l >> 4;
  const int NT = tile >> 4, kt = tile & 15;
  const int n  = NT*16 + m;
  const int k0 = kt*32 + 8*g;
  const float* src = W + n*HD + k0;
  _Float16 v[8];
  #pragma unroll
  for (int j=0;j<8;j++) v[j] = (_Float16)src[j];
  *((f16x8*)(Wp + (size_t)tile*512) + l) = *(const f16x8*)v;
}

// ---------------- ODE RK4 evolve via MFMA f16 ----------------
// 32 blocks x 512 thr (8 waves). Block owns rows [8b, 8b+8) (+8 zero pad rows).
// Wave w owns cols [64w, 64w+64) = 4 n-tiles. State X + RK4 accum in regs (D-layout).
__global__ __launch_bounds__(512,2) void k_ode(
    const float* __restrict__ h0, const float* __restrict__ tau,
    const _Float16* __restrict__ W1p, const float* __restrict__ b1,
    const _Float16* __restrict__ W2p, const float* __restrict__ b2,
    float* __restrict__ newh){
  __shared__ _Float16 V[16*VSTR];
  __shared__ _Float16 Y[16*VSTR];
  const int t = threadIdx.x;
  const int l = t & 63;
  const int w = t >> 6;         // wave 0..7
  const int m = l & 15;
  const int g = l >> 4;         // 0..3
  const int r0 = blockIdx.x * G;

  float X [4][4];   // [nt][r] : element (row=4g+r, col=w*64+nt*16+m)
  float ac[4][4];   // RK4 k1+2k2+2k3 accumulator
  float dtr[4];
  float bias1[4], bias2[4];

  #pragma unroll
  for (int r=0;r<4;r++){
    const int row = 4*g + r;
    dtr[r] = (row < G) ? tau[r0+row] * (1.0f/(float)KST) : 0.0f;
  }
  #pragma unroll
  for (int nt=0;nt<4;nt++){
    const int c = w*64 + nt*16 + m;
    bias1[nt] = b1[c];
    bias2[nt] = b2[c];
    #pragma unroll
    for (int r=0;r<4;r++){
      const int row = 4*g + r;
      const float x = (row < G) ? h0[(r0+row)*HD + c] : 0.0f;
      X[nt][r] = x;
      ac[nt][r] = 0.f;
      V[row*VSTR + c] = (_Float16)x;
    }
  }
  __syncthreads();

  for (int s=0;s<KST;s++){
    #pragma unroll
    for (int st=0;st<4;st++){
      // ---------- layer 1: Y = tanh(V @ W1^T + b1) ----------
      {
        f16x8 af[16];
        #pragma unroll
        for (int kt=0;kt<16;kt++)
          af[kt] = *(const f16x8*)&V[m*VSTR + kt*32 + 8*g];
        #pragma unroll
        for (int nt=0;nt<4;nt++){
          const int NT = w*4 + nt;
          const f16x8* bp = (const f16x8*)W1p + (size_t)(NT*16)*64 + l;
          f16x8 bb[16];
          #pragma unroll
          for (int kt=0;kt<16;kt++) bb[kt] = bp[(size_t)kt*64];
          f32x4 acc = {0.f,0.f,0.f,0.f};
          #pragma unroll
          for (int kt=0;kt<16;kt++)
            acc = __builtin_amdgcn_mfma_f32_16x16x32_f16(af[kt], bb[kt], acc, 0,0,0);
          #pragma unroll
          for (int r=0;r<4;r++)
            Y[(4*g+r)*VSTR + NT*16 + m] = (_Float16)tanhfast(acc[r] + bias1[nt]);
        }
      }
      __syncthreads();
      // ---------- layer 2: kv = Y @ W2^T + b2, RK4 update ----------
      {
        f16x8 af[16];
        #pragma unroll
        for (int kt=0;kt<16;kt++)
          af[kt] = *(const f16x8*)&Y[m*VSTR + kt*32 + 8*g];
        #pragma unroll
        for (int nt=0;nt<4;nt++){
          const int NT = w*4 + nt;
          const f16x8* bp = (const f16x8*)W2p + (size_t)(NT*16)*64 + l;
          f16x8 bb[16];
          #pragma unroll
          for (int kt=0;kt<16;kt++) bb[kt] = bp[(size_t)kt*64];
          f32x4 acc = {0.f,0.f,0.f,0.f};
          #pragma unroll
          for (int kt=0;kt<16;kt++)
            acc = __builtin_amdgcn_mfma_f32_16x16x32_f16(af[kt], bb[kt], acc, 0,0,0);
          #pragma unroll
          for (int r=0;r<4;r++){
            const float kv = acc[r] + bias2[nt];
            float v;
            if      (st==0){ ac[nt][r] = kv;        v = X[nt][r] + 0.5f*dtr[r]*kv; }
            else if (st==1){ ac[nt][r] += 2.f*kv;   v = X[nt][r] + 0.5f*dtr[r]*kv; }
            else if (st==2){ ac[nt][r] += 2.f*kv;   v = X[nt][r] + dtr[r]*kv;      }
            else           { X[nt][r] += (dtr[r]*(1.f/6.f))*(ac[nt][r] + kv); v = X[nt][r]; }
            V[(4*g+r)*VSTR + NT*16 + m] = (_Float16)v;
          }
        }
      }
      __syncthreads();
    }
  }

  #pragma unroll
  for (int nt=0;nt<4;nt++){
    const int c = w*64 + nt*16 + m;
    #pragma unroll
    for (int r=0;r<4;r++){
      const int row = 4*g + r;
      if (row < G) newh[(r0+row)*HD + c] = X[nt][r];
    }
  }
}

// ---------------- launcher ----------------
extern "C" void kernel_launch(void* const* d_in, const int* in_sizes, int n_in,
                              void* d_out, int out_size, void* d_ws, size_t ws_size,
                              hipStream_t stream){
  const float* inp = (const float*)d_in[0];
  const float* h   = (const float*)d_in[1];
  const float* c   = (const float*)d_in[2];
  const float* ts  = (const float*)d_in[3];
  const float* Wih = (const float*)d_in[4];
  const float* Whh = (const float*)d_in[5];
  const float* bih = (const float*)d_in[6];
  const float* bhh = (const float*)d_in[7];
  const float* W1  = (const float*)d_in[8];
  const float* b1  = (const float*)d_in[9];
  const float* W2  = (const float*)d_in[10];
  const float* b2  = (const float*)d_in[11];

  float* newh = (float*)d_out;            // [256,512]
  float* newc = (float*)d_out + BB*HD;    // [256,512]

  float*    h0  = (float*)d_ws;               // [256,512] fp32
  float*    tau = h0 + BB*HD;                 // [256]
  _Float16* W1p = (_Float16*)(tau + BB);      // [512*512] f16 packed
  _Float16* W2p = W1p + HD*HD;                // [512*512] f16 packed

  k_pack <<<512, 64, 0, stream>>>(W1, W1p);
  k_pack <<<512, 64, 0, stream>>>(W2, W2p);
  k_gates<<<BB/4, 256, 0, stream>>>(inp,h,c,Wih,Whh,bih,bhh,h0,newc);
  k_sort <<<1,   BB,  0, stream>>>(ts,tau);
  k_ode  <<<ODE_BLOCKS, 512, 0, stream>>>(h0,tau,W1p,b1,W2p,b2,newh);
}

// Round 3
// 1010.972 us; speedup vs baseline: 3.7611x; 1.8458x over previous
//
#include <hip/hip_runtime.h>

#define BB   256   // batch
#define IND  128   // input dim
#define HD   512   // hidden dim
#define KST  8     // uniform RK4 steps per row
#define G    8     // real rows per ode block
#define ODE_BLOCKS (BB/G)   // 32
#define VSTR 520   // padded LDS row stride in halfs (1040 B = 65*16, keeps b128 alignment)
#define XSTR 648   // gates LDS row stride in halfs (1296 B = 81*16)

typedef _Float16 f16x8 __attribute__((ext_vector_type(8)));
typedef float    f32x4 __attribute__((ext_vector_type(4)));

__device__ __forceinline__ float sigm(float x){ return 1.0f/(1.0f+__expf(-x)); }
__device__ __forceinline__ float tanhfast(float x){
  float e2 = __expf(2.0f*x);
  return 1.0f - 2.0f/(e2+1.0f);
}
__device__ __forceinline__ f16x8 cvt8(const float* s){
  f16x8 r;
  #pragma unroll
  for (int j=0;j<8;j++) r[j] = (_Float16)s[j];
  return r;
}

// ---------------- LSTM gates via MFMA ----------------
// 16 blocks x 512 thr (8 waves). Block owns batch rows [16b,16b+16).
// Wave w owns hidden cols [64w,64w+64) = 4 hi-tiles j; per (gate,j): col-tile NT = gate*32 + w*4 + j.
// Lane holds i/f/g/o for the same (row,hi) -> full cell epilogue in-register.
__global__ __launch_bounds__(512) void k_gates(
    const float* __restrict__ inp, const float* __restrict__ h,
    const float* __restrict__ c,   const float* __restrict__ Wih,
    const float* __restrict__ Whh, const float* __restrict__ bih,
    const float* __restrict__ bhh, float* __restrict__ h0,
    float* __restrict__ newc){
  __shared__ _Float16 X16[16*XSTR];
  const int t = threadIdx.x;
  const int l = t & 63;
  const int w = t >> 6;
  const int m = l & 15;
  const int g = l >> 4;
  const int r0 = blockIdx.x * 16;

  // stage [inp | h] rows as f16 (16 x 640)
  for (int i=0;i<20;i++){
    const int e  = t + 512*i;      // 0..10239
    const int rr = e / 640;
    const int k  = e - rr*640;
    const float v = (k < IND) ? inp[(r0+rr)*IND + k] : h[(r0+rr)*HD + (k-IND)];
    X16[rr*XSTR + k] = (_Float16)v;
  }
  __syncthreads();

  f32x4 acc[4][4];   // [gate][j]
  #pragma unroll
  for (int a=0;a<4;a++)
    #pragma unroll
    for (int b=0;b<4;b++) acc[a][b] = (f32x4){0.f,0.f,0.f,0.f};

  #pragma unroll
  for (int kt=0;kt<20;kt++){
    const f16x8 af = *(const f16x8*)&X16[m*XSTR + kt*32 + 8*g];
    #pragma unroll
    for (int gate=0;gate<4;gate++){
      #pragma unroll
      for (int j=0;j<4;j++){
        const int NT = gate*32 + w*4 + j;
        const int n  = NT*16 + m;
        const float* src = (kt<4) ? (Wih + n*IND + kt*32 + 8*g)
                                  : (Whh + n*HD  + (kt*32-IND) + 8*g);
        const f16x8 bb = cvt8(src);
        acc[gate][j] = __builtin_amdgcn_mfma_f32_16x16x32_f16(af, bb, acc[gate][j], 0,0,0);
      }
    }
  }

  #pragma unroll
  for (int j=0;j<4;j++){
    const int hi = (w*4+j)*16 + m;
    const float bI = bih[hi]        + bhh[hi];
    const float bF = bih[HD+hi]     + bhh[HD+hi];
    const float bG = bih[2*HD+hi]   + bhh[2*HD+hi];
    const float bO = bih[3*HD+hi]   + bhh[3*HD+hi];
    #pragma unroll
    for (int r=0;r<4;r++){
      const int row = r0 + 4*g + r;
      const float iv = acc[0][j][r] + bI;
      const float fv = acc[1][j][r] + bF;
      const float gv = acc[2][j][r] + bG;
      const float ov = acc[3][j][r] + bO;
      const float cv = c[row*HD + hi];
      const float nc = sigm(fv)*cv + sigm(iv)*tanhfast(gv);
      const float hv = sigm(ov)*tanhfast(nc);
      newc[row*HD + hi] = nc;
      h0[row*HD + hi]   = hv;
    }
  }
}

// ---------------- stable argsort + per-row integration duration ----------------
__global__ void k_sort(const float* __restrict__ ts, float* __restrict__ tau){
  __shared__ float sts[BB];
  __shared__ float ssort[BB];
  __shared__ int   sidx[BB];
  const int t = threadIdx.x;
  sts[t] = ts[t];
  __syncthreads();
  const float v = sts[t];
  int r = 0;
  for (int k=0;k<BB;k++){
    const float u = sts[k];
    r += (u < v) || (u == v && k < t);
  }
  ssort[r] = v + (float)r*(1e-4f/255.0f);
  sidx[r]  = t;
  __syncthreads();
  const int n = sidx[t];
  tau[t] = ssort[n] - ssort[0];
}

// ---------------- pack W (fp32 row-major [512][512]) into f16 MFMA B-fragment order ----
// tile = NT*16+kt; lane l holds W[NT*16+(l&15)][kt*32+8*(l>>4) + j], j=0..7
__global__ void k_pack(const float* __restrict__ W, _Float16* __restrict__ Wp){
  const int tile = blockIdx.x;     // 0..511
  const int l = threadIdx.x;       // 0..63
  const int m = l & 15, g = l >> 4;
  const int NT = tile >> 4, kt = tile & 15;
  const float* src = W + (NT*16 + m)*HD + kt*32 + 8*g;
  *((f16x8*)(Wp + tile*512) + l) = cvt8(src);
}

// ---------------- ODE RK4 evolve via MFMA f16 ----------------
// 32 blocks x 1024 thr (16 waves, 4/SIMD). Block owns rows [8b,8b+8) (+8 pad).
// Wave w owns cols [32w,32w+32) = 2 n-tiles. VGPR budget <=128.
__global__ __launch_bounds__(1024,4) void k_ode(
    const float* __restrict__ h0, const float* __restrict__ tau,
    const _Float16* __restrict__ W1p, const float* __restrict__ b1,
    const _Float16* __restrict__ W2p, const float* __restrict__ b2,
    float* __restrict__ newh){
  __shared__ _Float16 V[16*VSTR];
  __shared__ _Float16 Y[16*VSTR];
  const int t = threadIdx.x;
  const int l = t & 63;
  const int w = t >> 6;         // wave 0..15
  const int m = l & 15;
  const int g = l >> 4;         // 0..3

  const int r0 = blockIdx.x * G;

  float X [2][4];   // [nt][r]: element (row=4g+r, col=w*32+nt*16+m)
  float ac[2][4];
  float dtr[4];
  float b1v[2], b2v[2];

  #pragma unroll
  for (int r=0;r<4;r++){
    const int row = 4*g + r;
    dtr[r] = (row < G) ? tau[r0+row] * (1.0f/(float)KST) : 0.0f;
  }
  #pragma unroll
  for (int nt=0;nt<2;nt++){
    const int cc = w*32 + nt*16 + m;
    b1v[nt] = b1[cc];
    b2v[nt] = b2[cc];
    #pragma unroll
    for (int r=0;r<4;r++){
      const int row = 4*g + r;
      const float x = (row < G) ? h0[(r0+row)*HD + cc] : 0.0f;
      X[nt][r] = x;
      ac[nt][r] = 0.f;
      V[row*VSTR + cc] = (_Float16)x;
    }
  }
  __syncthreads();

  for (int s=0;s<KST;s++){
    #pragma unroll
    for (int st=0;st<4;st++){
      // ---------- layer 1: Y = tanh(V @ W1^T + b1) ----------
      {
        f32x4 acc0 = {0.f,0.f,0.f,0.f};
        f32x4 acc1 = {0.f,0.f,0.f,0.f};
        #pragma unroll
        for (int kh=0;kh<2;kh++){
          f16x8 af[8];
          #pragma unroll
          for (int kq=0;kq<8;kq++)
            af[kq] = *(const f16x8*)&V[m*VSTR + (kh*8+kq)*32 + 8*g];
          #pragma unroll
          for (int nt=0;nt<2;nt++){
            const f16x8* bp = (const f16x8*)W1p + ((2*w+nt)*16 + kh*8)*64 + l;
            f16x8 bb[8];
            #pragma unroll
            for (int kq=0;kq<8;kq++) bb[kq] = bp[kq*64];
            f32x4& A = nt ? acc1 : acc0;
            #pragma unroll
            for (int kq=0;kq<8;kq++)
              A = __builtin_amdgcn_mfma_f32_16x16x32_f16(af[kq], bb[kq], A, 0,0,0);
          }
        }
        #pragma unroll
        for (int nt=0;nt<2;nt++){
          const f32x4& A = nt ? acc1 : acc0;
          #pragma unroll
          for (int r=0;r<4;r++)
            Y[(4*g+r)*VSTR + (2*w+nt)*16 + m] = (_Float16)tanhfast(A[r] + b1v[nt]);
        }
      }
      __syncthreads();
      // ---------- layer 2: kv = Y @ W2^T + b2, RK4 update ----------
      {
        f32x4 acc0 = {0.f,0.f,0.f,0.f};
        f32x4 acc1 = {0.f,0.f,0.f,0.f};
        #pragma unroll
        for (int kh=0;kh<2;kh++){
          f16x8 af[8];
          #pragma unroll
          for (int kq=0;kq<8;kq++)
            af[kq] = *(const f16x8*)&Y[m*VSTR + (kh*8+kq)*32 + 8*g];
          #pragma unroll
          for (int nt=0;nt<2;nt++){
            const f16x8* bp = (const f16x8*)W2p + ((2*w+nt)*16 + kh*8)*64 + l;
            f16x8 bb[8];
            #pragma unroll
            for (int kq=0;kq<8;kq++) bb[kq] = bp[kq*64];
            f32x4& A = nt ? acc1 : acc0;
            #pragma unroll
            for (int kq=0;kq<8;kq++)
              A = __builtin_amdgcn_mfma_f32_16x16x32_f16(af[kq], bb[kq], A, 0,0,0);
          }
        }
        #pragma unroll
        for (int nt=0;nt<2;nt++){
          const f32x4& A = nt ? acc1 : acc0;
          #pragma unroll
          for (int r=0;r<4;r++){
            const float kv = A[r] + b2v[nt];
            float v;
            if      (st==0){ ac[nt][r] = kv;      v = X[nt][r] + 0.5f*dtr[r]*kv; }
            else if (st==1){ ac[nt][r] += 2.f*kv; v = X[nt][r] + 0.5f*dtr[r]*kv; }
            else if (st==2){ ac[nt][r] += 2.f*kv; v = X[nt][r] + dtr[r]*kv;      }
            else           { X[nt][r] += (dtr[r]*(1.f/6.f))*(ac[nt][r] + kv); v = X[nt][r]; }
            V[(4*g+r)*VSTR + (2*w+nt)*16 + m] = (_Float16)v;
          }
        }
      }
      __syncthreads();
    }
  }

  #pragma unroll
  for (int nt=0;nt<2;nt++){
    const int cc = w*32 + nt*16 + m;
    #pragma unroll
    for (int r=0;r<4;r++){
      const int row = 4*g + r;
      if (row < G) newh[(r0+row)*HD + cc] = X[nt][r];
    }
  }
}

// ---------------- launcher ----------------
extern "C" void kernel_launch(void* const* d_in, const int* in_sizes, int n_in,
                              void* d_out, int out_size, void* d_ws, size_t ws_size,
                              hipStream_t stream){
  const float* inp = (const float*)d_in[0];
  const float* h   = (const float*)d_in[1];
  const float* c   = (const float*)d_in[2];
  const float* ts  = (const float*)d_in[3];
  const float* Wih = (const float*)d_in[4];
  const float* Whh = (const float*)d_in[5];
  const float* bih = (const float*)d_in[6];
  const float* bhh = (const float*)d_in[7];
  const float* W1  = (const float*)d_in[8];
  const float* b1  = (const float*)d_in[9];
  const float* W2  = (const float*)d_in[10];
  const float* b2  = (const float*)d_in[11];

  float* newh = (float*)d_out;            // [256,512]
  float* newc = (float*)d_out + BB*HD;    // [256,512]

  float*    h0  = (float*)d_ws;               // [256,512] fp32
  float*    tau = h0 + BB*HD;                 // [256]
  _Float16* W1p = (_Float16*)(tau + BB);      // [512*512] f16 packed
  _Float16* W2p = W1p + HD*HD;                // [512*512] f16 packed

  k_pack <<<512, 64, 0, stream>>>(W1, W1p);
  k_pack <<<512, 64, 0, stream>>>(W2, W2p);
  k_gates<<<BB/16, 512, 0, stream>>>(inp,h,c,Wih,Whh,bih,bhh,h0,newc);
  k_sort <<<1,   BB,  0, stream>>>(ts,tau);
  k_ode  <<<ODE_BLOCKS, 1024, 0, stream>>>(h0,tau,W1p,b1,W2p,b2,newh);
}

// Round 5
// 898.665 us; speedup vs baseline: 4.2312x; 1.1250x over previous
//
#include <hip/hip_runtime.h>

#define BB   256   // batch
#define IND  128   // input dim
#define HD   512   // hidden dim
#define KST  8     // uniform RK4 steps per row
#define G    8     // real rows per ode block
#define ODE_BLOCKS (BB/G)   // 32
#define VSTR 520   // padded LDS row stride in halfs
#define XSTR 648   // gates LDS row stride in halfs

typedef _Float16 f16x8 __attribute__((ext_vector_type(8)));
typedef float    f32x4 __attribute__((ext_vector_type(4)));

__device__ __forceinline__ float sigm(float x){ return 1.0f/(1.0f+__expf(-x)); }
__device__ __forceinline__ float tanhfast(float x){
  float e2 = __expf(2.0f*x);
  return 1.0f - 2.0f/(e2+1.0f);
}
__device__ __forceinline__ f16x8 cvt8(const float* s){
  f16x8 r;
  #pragma unroll
  for (int j=0;j<8;j++) r[j] = (_Float16)s[j];
  return r;
}

// ---------------- LSTM gates via MFMA, col-split across 4x blocks ----------------
// 64 blocks = (rt 0..15, cq 0..3) x 512 thr (8 waves). Block: rows [16rt,16rt+16),
// hidden cols [128cq,128cq+128). Wave w owns hid-tile ct = cq*8+w (16 cols),
// computing all 4 gates for those cols -> in-register cell epilogue.
__global__ __launch_bounds__(512) void k_gates(
    const float* __restrict__ inp, const float* __restrict__ h,
    const float* __restrict__ c,   const float* __restrict__ Wih,
    const float* __restrict__ Whh, const float* __restrict__ bih,
    const float* __restrict__ bhh, float* __restrict__ h0,
    float* __restrict__ newc){
  __shared__ _Float16 X16[16*XSTR];
  const int t = threadIdx.x;
  const int l = t & 63;
  const int w = t >> 6;          // 0..7
  const int m = l & 15;
  const int g = l >> 4;
  const int rt = blockIdx.x & 15;
  const int cq = blockIdx.x >> 4;
  const int r0 = rt * 16;
  const int ct = cq*8 + w;       // hidden col tile 0..31

  // stage [inp | h] rows as f16 (16 x 640)
  for (int i=0;i<20;i++){
    const int e  = t + 512*i;
    const int rr = e / 640;
    const int k  = e - rr*640;
    const float v = (k < IND) ? inp[(r0+rr)*IND + k] : h[(r0+rr)*HD + (k-IND)];
    X16[rr*XSTR + k] = (_Float16)v;
  }
  __syncthreads();

  f32x4 acc[4];  // [gate]
  #pragma unroll
  for (int a=0;a<4;a++) acc[a] = (f32x4){0.f,0.f,0.f,0.f};

  #pragma unroll
  for (int kt=0;kt<20;kt++){
    const f16x8 af = *(const f16x8*)&X16[m*XSTR + kt*32 + 8*g];
    #pragma unroll
    for (int gate=0;gate<4;gate++){
      const int n = (gate*32 + ct)*16 + m;
      const float* src = (kt<4) ? (Wih + n*IND + kt*32 + 8*g)
                                : (Whh + n*HD  + (kt*32-IND) + 8*g);
      const f16x8 bb = cvt8(src);
      acc[gate] = __builtin_amdgcn_mfma_f32_16x16x32_f16(af, bb, acc[gate], 0,0,0);
    }
  }

  const int hi = ct*16 + m;
  const float bI = bih[hi]      + bhh[hi];
  const float bF = bih[HD+hi]   + bhh[HD+hi];
  const float bG = bih[2*HD+hi] + bhh[2*HD+hi];
  const float bO = bih[3*HD+hi] + bhh[3*HD+hi];
  #pragma unroll
  for (int r=0;r<4;r++){
    const int row = r0 + 4*g + r;
    const float iv = acc[0][r] + bI;
    const float fv = acc[1][r] + bF;
    const float gv = acc[2][r] + bG;
    const float ov = acc[3][r] + bO;
    const float cv = c[row*HD + hi];
    const float nc = sigm(fv)*cv + sigm(iv)*tanhfast(gv);
    const float hv = sigm(ov)*tanhfast(nc);
    newc[row*HD + hi] = nc;
    h0[row*HD + hi]   = hv;
  }
}

// ---------------- stable argsort + per-row integration duration ----------------
__global__ void k_sort(const float* __restrict__ ts, float* __restrict__ tau){
  __shared__ float sts[BB];
  __shared__ float ssort[BB];
  __shared__ int   sidx[BB];
  const int t = threadIdx.x;
  sts[t] = ts[t];
  __syncthreads();
  const float v = sts[t];
  int r = 0;
  for (int k=0;k<BB;k++){
    const float u = sts[k];
    r += (u < v) || (u == v && k < t);
  }
  ssort[r] = v + (float)r*(1e-4f/255.0f);
  sidx[r]  = t;
  __syncthreads();
  const int n = sidx[t];
  tau[t] = ssort[n] - ssort[0];
}

// ---------------- pack W into f16 MFMA B-fragment order ----------------
// tile = NT*16+kt; lane l holds W[NT*16+(l&15)][kt*32+8*(l>>4)+j], j=0..7
__global__ void k_pack(const float* __restrict__ W, _Float16* __restrict__ Wp){
  const int tile = blockIdx.x;     // 0..511
  const int l = threadIdx.x;       // 0..63
  const int m = l & 15, g = l >> 4;
  const int NT = tile >> 4, kt = tile & 15;
  const float* src = W + (NT*16 + m)*HD + kt*32 + 8*g;
  *((f16x8*)(Wp + tile*512) + l) = cvt8(src);
}

// ---------------- one layer matvec: acc{0,1} += SRC(16x512) @ Wp-tiles(2w,2w+1) ----
// Double-buffered B prefetch, batch = 2 kt x 2 tiles = 4 loads in flight.
// All buffer indices compile-time constant after full unroll (no scratch).
__device__ __forceinline__ void layer_mv(const _Float16* __restrict__ SRC,
    const f16x8* __restrict__ bp0, const f16x8* __restrict__ bp1,
    const int m, const int g, f32x4& acc0, f32x4& acc1){
  f16x8 bA[2][2], bB[2][2];   // [parity][kq]
  #pragma unroll
  for (int kq=0;kq<2;kq++){ bA[0][kq] = bp0[kq*64]; bB[0][kq] = bp1[kq*64]; }
  #pragma unroll
  for (int kb=0;kb<8;kb++){
    const int cur = kb & 1, nxt = cur ^ 1;
    if (kb < 7){
      #pragma unroll
      for (int kq=0;kq<2;kq++){
        bA[nxt][kq] = bp0[((kb+1)*2+kq)*64];
        bB[nxt][kq] = bp1[((kb+1)*2+kq)*64];
      }
    }
    f16x8 af[2];
    #pragma unroll
    for (int kq=0;kq<2;kq++)
      af[kq] = *(const f16x8*)&SRC[m*VSTR + (kb*2+kq)*32 + 8*g];
    #pragma unroll
    for (int kq=0;kq<2;kq++){
      acc0 = __builtin_amdgcn_mfma_f32_16x16x32_f16(af[kq], bA[cur][kq], acc0, 0,0,0);
      acc1 = __builtin_amdgcn_mfma_f32_16x16x32_f16(af[kq], bB[cur][kq], acc1, 0,0,0);
    }
  }
}

// ---------------- ODE RK4 evolve via MFMA f16 ----------------
// 32 blocks x 1024 thr (16 waves). Block owns rows [8b,8b+8) (+8 pad).
// Wave w owns cols [32w,32w+32) = 2 n-tiles.
__global__ __launch_bounds__(1024,4) void k_ode(
    const float* __restrict__ h0, const float* __restrict__ tau,
    const _Float16* __restrict__ W1p, const float* __restrict__ b1,
    const _Float16* __restrict__ W2p, const float* __restrict__ b2,
    float* __restrict__ newh){
  __shared__ _Float16 V[16*VSTR];
  __shared__ _Float16 Y[16*VSTR];
  const int t = threadIdx.x;
  const int l = t & 63;
  const int w = t >> 6;         // wave 0..15
  const int m = l & 15;
  const int g = l >> 4;         // 0..3
  const int r0 = blockIdx.x * G;

  const f16x8* b1p0 = (const f16x8*)W1p + (2*w+0)*16*64 + l;
  const f16x8* b1p1 = (const f16x8*)W1p + (2*w+1)*16*64 + l;
  const f16x8* b2p0 = (const f16x8*)W2p + (2*w+0)*16*64 + l;
  const f16x8* b2p1 = (const f16x8*)W2p + (2*w+1)*16*64 + l;

  float X [2][4];   // [nt][r]: element (row=4g+r, col=w*32+nt*16+m)
  float ac[2][4];
  float dtr[4];
  float b1v[2], b2v[2];

  #pragma unroll
  for (int r=0;r<4;r++){
    const int row = 4*g + r;
    dtr[r] = (row < G) ? tau[r0+row] * (1.0f/(float)KST) : 0.0f;
  }
  #pragma unroll
  for (int nt=0;nt<2;nt++){
    const int cc = w*32 + nt*16 + m;
    b1v[nt] = b1[cc];
    b2v[nt] = b2[cc];
    #pragma unroll
    for (int r=0;r<4;r++){
      const int row = 4*g + r;
      const float x = (row < G) ? h0[(r0+row)*HD + cc] : 0.0f;
      X[nt][r] = x;
      ac[nt][r] = 0.f;
      V[row*VSTR + cc] = (_Float16)x;
    }
  }
  __syncthreads();

  for (int s=0;s<KST;s++){
    #pragma unroll
    for (int st=0;st<4;st++){
      // ---------- layer 1: Y = tanh(V @ W1^T + b1) ----------
      {
        f32x4 a0 = {0.f,0.f,0.f,0.f}, a1 = {0.f,0.f,0.f,0.f};
        layer_mv(V, b1p0, b1p1, m, g, a0, a1);
        #pragma unroll
        for (int r=0;r<4;r++){
          Y[(4*g+r)*VSTR + (2*w+0)*16 + m] = (_Float16)tanhfast(a0[r] + b1v[0]);
          Y[(4*g+r)*VSTR + (2*w+1)*16 + m] = (_Float16)tanhfast(a1[r] + b1v[1]);
        }
      }
      __syncthreads();
      // ---------- layer 2: kv = Y @ W2^T + b2, RK4 update ----------
      {
        f32x4 a0 = {0.f,0.f,0.f,0.f}, a1 = {0.f,0.f,0.f,0.f};
        layer_mv(Y, b2p0, b2p1, m, g, a0, a1);
        #pragma unroll
        for (int nt=0;nt<2;nt++){
          #pragma unroll
          for (int r=0;r<4;r++){
            const float kv = (nt ? a1[r] : a0[r]) + b2v[nt];
            float v;
            if      (st==0){ ac[nt][r] = kv;      v = X[nt][r] + 0.5f*dtr[r]*kv; }
            else if (st==1){ ac[nt][r] += 2.f*kv; v = X[nt][r] + 0.5f*dtr[r]*kv; }
            else if (st==2){ ac[nt][r] += 2.f*kv; v = X[nt][r] + dtr[r]*kv;      }
            else           { X[nt][r] += (dtr[r]*(1.f/6.f))*(ac[nt][r] + kv); v = X[nt][r]; }
            V[(4*g+r)*VSTR + (2*w+nt)*16 + m] = (_Float16)v;
          }
        }
      }
      __syncthreads();
    }
  }

  #pragma unroll
  for (int nt=0;nt<2;nt++){
    const int cc = w*32 + nt*16 + m;
    #pragma unroll
    for (int r=0;r<4;r++){
      const int row = 4*g + r;
      if (row < G) newh[(r0+row)*HD + cc] = X[nt][r];
    }
  }
}

// ---------------- launcher ----------------
extern "C" void kernel_launch(void* const* d_in, const int* in_sizes, int n_in,
                              void* d_out, int out_size, void* d_ws, size_t ws_size,
                              hipStream_t stream){
  const float* inp = (const float*)d_in[0];
  const float* h   = (const float*)d_in[1];
  const float* c   = (const float*)d_in[2];
  const float* ts  = (const float*)d_in[3];
  const float* Wih = (const float*)d_in[4];
  const float* Whh = (const float*)d_in[5];
  const float* bih = (const float*)d_in[6];
  const float* bhh = (const float*)d_in[7];
  const float* W1  = (const float*)d_in[8];
  const float* b1  = (const float*)d_in[9];
  const float* W2  = (const float*)d_in[10];
  const float* b2  = (const float*)d_in[11];

  float* newh = (float*)d_out;            // [256,512]
  float* newc = (float*)d_out + BB*HD;    // [256,512]

  float*    h0  = (float*)d_ws;               // [256,512] fp32
  float*    tau = h0 + BB*HD;                 // [256]
  _Float16* W1p = (_Float16*)(tau + BB);      // [512*512] f16 packed
  _Float16* W2p = W1p + HD*HD;                // [512*512] f16 packed

  k_pack <<<512, 64, 0, stream>>>(W1, W1p);
  k_pack <<<512, 64, 0, stream>>>(W2, W2p);
  k_gates<<<64, 512, 0, stream>>>(inp,h,c,Wih,Whh,bih,bhh,h0,newc);
  k_sort <<<1,  BB,  0, stream>>>(ts,tau);
  k_ode  <<<ODE_BLOCKS, 1024, 0, stream>>>(h0,tau,W1p,b1,W2p,b2,newh);
}